// Round 9
// baseline (318.201 us; speedup 1.0000x reference)
//
#include <hip/hip_runtime.h>
#include <hip/hip_bf16.h>

#define NB 8
#define PP 256
#define CC 128
#define XS 132     // padded row stride for qkv x-tile (f32 elems)

typedef __attribute__((ext_vector_type(8))) unsigned short ushort8;
typedef _Float16 f16x8 __attribute__((ext_vector_type(8)));
typedef _Float16 h2v __attribute__((ext_vector_type(2)));
typedef float float4v __attribute__((ext_vector_type(4)));

__device__ __forceinline__ float bf2f(unsigned short u) {
    union { unsigned int i; float f; } x; x.i = ((unsigned int)u) << 16; return x.f;
}
__device__ __forceinline__ unsigned short f2bf(float f) {
    union { float f; unsigned int i; } x; x.f = f;
    unsigned int r = x.i + 0x7fffu + ((x.i >> 16) & 1u);  // RNE
    return (unsigned short)(r >> 16);
}

// blocks 0..127: Wq1 = Wq@W1 (f32); 128..255: Wk1 = Wk@W1 (f32);
// 256..383: W21f = (Wp2@W1) in fp16 MFMA-fragment order; block 384: bvec.
// Fragment order: k=kk*32+quad*8+e, col=jt*16+ln, lane=quad*16+ln:
//   idx = (((kk*8+jt)*64)+lane)*8 + e
__global__ void prep_kernel(const float* __restrict__ Wq, const float* __restrict__ Wk,
                            const float* __restrict__ Wp2, const float* __restrict__ W1,
                            const float* __restrict__ b1, const float* __restrict__ bp2,
                            float* __restrict__ Wq1, float* __restrict__ Wk1,
                            unsigned short* __restrict__ W21f, float* __restrict__ bvec) {
    int bx = blockIdx.x, j = threadIdx.x;
    __shared__ float xr[CC];
    if (bx < 384) {
        int r = bx & 127;
        const float* X = (bx < 128) ? Wq : (bx < 256) ? Wk : Wp2;
        xr[j] = X[r * CC + j];
        __syncthreads();
        float s = 0.f;
#pragma unroll 4
        for (int t = 0; t < CC; ++t) s = fmaf(xr[t], W1[t * CC + j], s);
        if (bx < 128)      Wq1[r * CC + j] = s;
        else if (bx < 256) Wk1[r * CC + j] = s;
        else {
            int k = r;
            int kk = k >> 5, quad = (k >> 3) & 3, e = k & 7;
            int jt = j >> 4, ln = j & 15;
            int lane = quad * 16 + ln;
            union { _Float16 h; unsigned short u; } cv;
            cv.h = (_Float16)s;
            W21f[(((kk * 8 + jt) * 64) + lane) * 8 + e] = cv.u;
        }
    } else {
        float s = b1[j];
        for (int c = 0; c < CC; ++c) s = fmaf(bp2[c], W1[c * CC + j], s);
        bvec[j] = s;
    }
}

// which==0: qwtb[n][j][b] = bf16( (x@Wq1)[n,b][j] )  (transposed, bf16)
// which==1: kw = x@Wk1 (f32);  which==2: v = x@Wv (f32)
__global__ __launch_bounds__(256) void qkv_kernel(
    const float* __restrict__ x, const float* __restrict__ Wq1,
    const float* __restrict__ Wk1, const float* __restrict__ Wv,
    unsigned short* __restrict__ qwtb, float* __restrict__ kw,
    float* __restrict__ v) {
    __shared__ float Ws[CC * CC];
    __shared__ float xs[32 * XS];
    int t = threadIdx.x, which = blockIdx.y;
    const float* W = (which == 0) ? Wq1 : (which == 1) ? Wk1 : Wv;
    int row0 = blockIdx.x * 32;
#pragma unroll 8
    for (int i = 0; i < 64; ++i) Ws[i * 256 + t] = W[i * 256 + t];
#pragma unroll 4
    for (int i = 0; i < 16; ++i) {
        int idx = i * 256 + t;
        int r = idx >> 7, c = idx & 127;
        xs[r * XS + c] = x[(size_t)(row0 + r) * CC + c];
    }
    __syncthreads();
    int tc = t & 31, tr = t >> 5;
    int j0 = tc * 4, r0 = tr * 4;
    float acc[4][4];
#pragma unroll
    for (int i = 0; i < 4; ++i)
#pragma unroll
        for (int jj = 0; jj < 4; ++jj) acc[i][jj] = 0.f;
#pragma unroll 2
    for (int c = 0; c < CC; ++c) {
        float4 w4 = *(const float4*)&Ws[c * CC + j0];
        float x0 = xs[(r0 + 0) * XS + c], x1 = xs[(r0 + 1) * XS + c];
        float x2 = xs[(r0 + 2) * XS + c], x3 = xs[(r0 + 3) * XS + c];
        acc[0][0] = fmaf(x0, w4.x, acc[0][0]); acc[0][1] = fmaf(x0, w4.y, acc[0][1]);
        acc[0][2] = fmaf(x0, w4.z, acc[0][2]); acc[0][3] = fmaf(x0, w4.w, acc[0][3]);
        acc[1][0] = fmaf(x1, w4.x, acc[1][0]); acc[1][1] = fmaf(x1, w4.y, acc[1][1]);
        acc[1][2] = fmaf(x1, w4.z, acc[1][2]); acc[1][3] = fmaf(x1, w4.w, acc[1][3]);
        acc[2][0] = fmaf(x2, w4.x, acc[2][0]); acc[2][1] = fmaf(x2, w4.y, acc[2][1]);
        acc[2][2] = fmaf(x2, w4.z, acc[2][2]); acc[2][3] = fmaf(x2, w4.w, acc[2][3]);
        acc[3][0] = fmaf(x3, w4.x, acc[3][0]); acc[3][1] = fmaf(x3, w4.y, acc[3][1]);
        acc[3][2] = fmaf(x3, w4.z, acc[3][2]); acc[3][3] = fmaf(x3, w4.w, acc[3][3]);
    }
    if (which == 0) {
        int n = row0 >> 8, b0 = row0 & 255;
#pragma unroll
        for (int jj = 0; jj < 4; ++jj) {
            ushort4 pk;
            pk.x = f2bf(acc[0][jj]); pk.y = f2bf(acc[1][jj]);
            pk.z = f2bf(acc[2][jj]); pk.w = f2bf(acc[3][jj]);
            *(ushort4*)(qwtb + (size_t)(n * CC + j0 + jj) * PP + b0 + r0) = pk;
        }
    } else {
        float* o = (which == 1) ? kw : v;
#pragma unroll
        for (int i = 0; i < 4; ++i)
            *(float4*)&o[(size_t)(row0 + r0 + i) * CC + j0] =
                make_float4(acc[i][0], acc[i][1], acc[i][2], acc[i][3]);
    }
}

// One block per (n,a). fp16 MFMA; A built in regs w/ packed-f16 vector math; B in
// fragment-order LDS (conflict-free b128); AV loop float4-vectorized.
__global__ __launch_bounds__(256, 3) void attn_kernel(
    const float* __restrict__ x, const float* __restrict__ pos,
    const float* __restrict__ Wp1, const float* __restrict__ bp1,
    const float* __restrict__ W2, const float* __restrict__ b2,
    const unsigned short* __restrict__ W21f, const float* __restrict__ bvec,
    const unsigned short* __restrict__ qwtb, const float* __restrict__ kw,
    const float* __restrict__ v, float* __restrict__ out)
{
    __shared__ __attribute__((aligned(16))) unsigned short Bs[128 * 128]; // frag order
    __shared__ float p0s[PP], p1s[PP];
    __shared__ float logits[PP];
    __shared__ float red[8];
    __shared__ float avp[8 * 128];

    const int t = threadIdx.x;
    const int n = blockIdx.x >> 8, a = blockIdx.x & 255;
    const int lane = t & 63, wv = t >> 6;
    const int ln = lane & 15, quad = lane >> 4;

    {
        const float2* pr = (const float2*)(pos + (size_t)(n * PP + a) * PP * 2);
        float2 pp = pr[t];
        p0s[t] = pp.x;
        p1s[t] = pp.y;
    }
    {   // stage Bs: straight 16B copies (global coalesced, LDS conflict-free)
        const uint4* src = (const uint4*)W21f;
        uint4* dst = (uint4*)Bs;
#pragma unroll
        for (int i = 0; i < 8; ++i) dst[i * 256 + t] = src[i * 256 + t];
    }
    const float b2f = b2[0];

    // A-operand constants in registers: k-slice for this lane's quad
    // k = kk*32 + quad*8 + p*2 (+1)
    h2v wa2[16], wb2[16], bp2h[16];
#pragma unroll
    for (int kk = 0; kk < 4; ++kk)
#pragma unroll
        for (int p = 0; p < 4; ++p) {
            int k = kk * 32 + quad * 8 + p * 2;
            wa2[kk * 4 + p]  = (h2v){(_Float16)Wp1[k],      (_Float16)Wp1[k + 1]};
            wb2[kk * 4 + p]  = (h2v){(_Float16)Wp1[CC + k], (_Float16)Wp1[CC + k + 1]};
            bp2h[kk * 4 + p] = (h2v){(_Float16)bp1[k],      (_Float16)bp1[k + 1]};
        }

    // per-lane epilogue constants (col j = nt*16 + ln)
    float w2v[8], kbv[8];
    {
        const float* kwrow = kw + (size_t)(n * PP + a) * CC;
#pragma unroll
        for (int nt = 0; nt < 8; ++nt) {
            int j = nt * 16 + ln;
            w2v[nt] = W2[j];
            kbv[nt] = bvec[j] - kwrow[j];
        }
    }
    const h2v z2 = (h2v){(_Float16)0.f, (_Float16)0.f};
    __syncthreads();

#pragma unroll 1
    for (int chunk = 0; chunk < 4; ++chunk) {
        const int rbase = chunk * 64 + wv * 16;
        const _Float16 p0h = (_Float16)p0s[rbase + ln];
        const _Float16 p1h = (_Float16)p1s[rbase + ln];
        const h2v P0h = (h2v){p0h, p0h};
        const h2v P1h = (h2v){p1h, p1h};

        // prefetch qw epilogue values (bf16 transposed [n][j][b])
        ushort4 qv4[8];
#pragma unroll
        for (int nt = 0; nt < 8; ++nt)
            qv4[nt] = *(const ushort4*)(qwtb + (size_t)(n * CC + nt * 16 + ln) * PP
                                        + rbase + quad * 4);

        float4v acc[8];
#pragma unroll
        for (int j = 0; j < 8; ++j) acc[j] = (float4v)0.f;

#pragma unroll 1
        for (int kk = 0; kk < 4; ++kk) {
            union { f16x8 v8; h2v h2[4]; } A;
#pragma unroll
            for (int p = 0; p < 4; ++p)
                A.h2[p] = __builtin_elementwise_max(
                    P0h * wa2[kk * 4 + p] + P1h * wb2[kk * 4 + p] + bp2h[kk * 4 + p], z2);
#pragma unroll
            for (int j = 0; j < 8; ++j) {
                f16x8 bfr = *(const f16x8*)(Bs + (((kk * 8 + j) * 64) + lane) * 8);
                acc[j] = __builtin_amdgcn_mfma_f32_16x16x32_f16(A.v8, bfr, acc[j], 0, 0, 0);
            }
        }

        // epilogue: D row = quad*4 + r, col = nt*16 + ln
        float s0 = 0.f, s1 = 0.f, s2 = 0.f, s3 = 0.f;
#pragma unroll
        for (int nt = 0; nt < 8; ++nt) {
            float kb = kbv[nt], w2 = w2v[nt];
            s0 = fmaf(fmaxf(acc[nt][0] + bf2f(qv4[nt].x) + kb, 0.f), w2, s0);
            s1 = fmaf(fmaxf(acc[nt][1] + bf2f(qv4[nt].y) + kb, 0.f), w2, s1);
            s2 = fmaf(fmaxf(acc[nt][2] + bf2f(qv4[nt].z) + kb, 0.f), w2, s2);
            s3 = fmaf(fmaxf(acc[nt][3] + bf2f(qv4[nt].w) + kb, 0.f), w2, s3);
        }
        float sr[4] = {s0, s1, s2, s3};
#pragma unroll
        for (int r = 0; r < 4; ++r) {
            float s = sr[r];
            s += __shfl_xor(s, 1);
            s += __shfl_xor(s, 2);
            s += __shfl_xor(s, 4);
            s += __shfl_xor(s, 8);
            if (ln == 0) logits[rbase + quad * 4 + r] = s + b2f;
        }
    }
    __syncthreads();   // logits ready

    // ---- softmax over 256 logits: wave shfl reductions ----
    float lv = logits[t];
    float wm = lv;
#pragma unroll
    for (int d = 1; d < 64; d <<= 1) wm = fmaxf(wm, __shfl_xor(wm, d));
    if (lane == 0) red[wv] = wm;
    __syncthreads();
    float m = fmaxf(fmaxf(red[0], red[1]), fmaxf(red[2], red[3]));
    float e = __expf(lv - m);
    float es = e;
#pragma unroll
    for (int d = 1; d < 64; d <<= 1) es += __shfl_xor(es, d);
    if (lane == 0) red[4 + wv] = es;
    __syncthreads();
    float denom = red[4] + red[5] + red[6] + red[7];
    logits[t] = e / denom;
    __syncthreads();

    // ---- out[n,a,c] = x[n,a,c] + sum_b att[b] * v[n,b,c], float4 over c ----
    {
        int c4 = (t & 31) * 4, bg = t >> 5;          // 8 b-groups of 32
        const float* vp = v + (size_t)(n * PP + bg * 32) * CC + c4;
        float4 av = make_float4(0.f, 0.f, 0.f, 0.f);
#pragma unroll 4
        for (int b = 0; b < 32; ++b) {
            float w = logits[bg * 32 + b];
            float4 vv = *(const float4*)(vp + (size_t)b * CC);
            av.x = fmaf(w, vv.x, av.x); av.y = fmaf(w, vv.y, av.y);
            av.z = fmaf(w, vv.z, av.z); av.w = fmaf(w, vv.w, av.w);
        }
        *(float4*)&avp[bg * 128 + c4] = av;
    }
    __syncthreads();
    if (t < 128) {
        int oidx = (n * PP + a) * CC + t;
        float s = x[oidx];
#pragma unroll
        for (int g = 0; g < 8; ++g) s += avp[g * 128 + t];
        out[oidx] = s;
    }
}

extern "C" void kernel_launch(void* const* d_in, const int* in_sizes, int n_in,
                              void* d_out, int out_size, void* d_ws, size_t ws_size,
                              hipStream_t stream) {
    const float* x   = (const float*)d_in[0];
    const float* pos = (const float*)d_in[1];
    const float* Wq  = (const float*)d_in[2];
    const float* Wk  = (const float*)d_in[3];
    const float* Wv  = (const float*)d_in[4];
    const float* W1  = (const float*)d_in[5];
    const float* b1  = (const float*)d_in[6];
    const float* W2  = (const float*)d_in[7];
    const float* b2  = (const float*)d_in[8];
    const float* Wp1 = (const float*)d_in[9];
    const float* bp1 = (const float*)d_in[10];
    const float* Wp2 = (const float*)d_in[11];
    const float* bp2 = (const float*)d_in[12];
    float* out = (float*)d_out;

    float* ws   = (float*)d_ws;
    float* Wq1  = ws;                  // 16384 f32
    float* Wk1  = Wq1 + 16384;         // 16384 f32
    float* bvec = Wk1 + 16384;         // 128 f32
    float* kw   = bvec + 128;          // 262144 f32
    float* v    = kw + 262144;         // 262144 f32
    unsigned short* qwtb = (unsigned short*)(v + 262144);  // 262144 bf16
    unsigned short* W21f = qwtb + 262144;                  // 16384 fp16 (frag order)

    prep_kernel<<<385, 128, 0, stream>>>(Wq, Wk, Wp2, W1, b1, bp2, Wq1, Wk1, W21f, bvec);
    qkv_kernel<<<dim3(64, 3), 256, 0, stream>>>(x, Wq1, Wk1, Wv, qwtb, kw, v);
    attn_kernel<<<NB * PP, 256, 0, stream>>>(x, pos, Wp1, bp1, W2, b2,
                                             W21f, bvec, qwtb, kw, v, out);
}